// Round 5
// baseline (171.571 us; speedup 1.0000x reference)
//
#include <hip/hip_runtime.h>
#include <hip/hip_bf16.h>

// SAGAN self-attention, B=16, C=128, H=W=64. Inputs fp32, output fp32.
// ws layout in ushorts (bf16):
//   U_WN  = 0        : Wn bf16 [96][128] (theta 0..15, phi 16..31, g 32..95)
//   U_WO  = 12288    : Wo bf16 [128][64]
//   U_TH  = 20480    : thetaT bf16 [16 b][4096 s][16 c]
//   U_PHI = 1069056  : phiT   bf16 [16 b][1024 t][16 c]
//   U_G   = 1331200  : g      bf16 [16 b][64 c][1024 t]
//   U_OT  = 2379776  : oT     bf16 [16 b][4096 s][64 c]

#define U_WN  0
#define U_WO  12288
#define U_TH  20480
#define U_PHI 1069056
#define U_G   1331200
#define U_OT  2379776

typedef __attribute__((ext_vector_type(8)))  short bf16x8;
typedef __attribute__((ext_vector_type(4)))  short s16x4;
typedef __attribute__((ext_vector_type(4)))  float f32x4;
typedef __attribute__((ext_vector_type(16))) float f32x16;

__device__ inline unsigned short f2b(float f) {
    union { float f; unsigned u; } v; v.f = f;
    unsigned r = v.u + 0x7FFFu + ((v.u >> 16) & 1u);   // RNE
    return (unsigned short)(r >> 16);
}
__device__ inline unsigned short f2b_trunc(float f) {
    union { float f; unsigned u; } v; v.f = f;
    return (unsigned short)(v.u >> 16);                // RTZ: 1 instr, ok for P
}
__device__ inline float b2f(unsigned short u) {
    union { unsigned u; float f; } v; v.u = ((unsigned)u) << 16; return v.f;
}

// ---------------- Kernel A: spectral norm, emit bf16 weights ----------------
__global__ __launch_bounds__(256) void sn4(
        const float* __restrict__ w0, const float* __restrict__ w1,
        const float* __restrict__ w2, const float* __restrict__ w3,
        const float* __restrict__ u0, const float* __restrict__ u1,
        const float* __restrict__ u2, const float* __restrict__ u3,
        unsigned short* __restrict__ wsu) {
    int wi = blockIdx.x;
    const float* W; const float* u; unsigned short* dst; int on, in_;
    if      (wi == 0) { W = w0; u = u0; dst = wsu;          on = 16;  in_ = 128; }
    else if (wi == 1) { W = w1; u = u1; dst = wsu + 2048;   on = 16;  in_ = 128; }
    else if (wi == 2) { W = w2; u = u2; dst = wsu + 4096;   on = 64;  in_ = 128; }
    else              { W = w3; u = u3; dst = wsu + 12288;  on = 128; in_ = 64;  }
    __shared__ float Wl[8320];    // [on][in_+1]
    __shared__ float ul[128];
    __shared__ float v[128];
    __shared__ float red[256];
    __shared__ float s_inv;
    int tid = threadIdx.x;
    int n = on * in_;
    int stride = in_ + 1;
    int shift = (in_ == 128) ? 7 : 6;
    int mask = in_ - 1;
    for (int i = tid; i < n; i += 256) {
        int o = i >> shift, j = i & mask;
        Wl[o * stride + j] = W[i];
    }
    if (tid < on) ul[tid] = u[tid];
    __syncthreads();
    float vi = 0.f;
    if (tid < in_) {
        for (int o = 0; o < on; ++o) vi += ul[o] * Wl[o * stride + tid];
    }
    red[tid] = (tid < in_) ? vi * vi : 0.f;
    __syncthreads();
    for (int st = 128; st > 0; st >>= 1) {
        if (tid < st) red[tid] += red[tid + st];
        __syncthreads();
    }
    float inv_nv = 1.0f / fmaxf(sqrtf(red[0]), 1e-12f);
    __syncthreads();
    if (tid < in_) v[tid] = vi * inv_nv;
    __syncthreads();
    float ui = 0.f;
    if (tid < on) {
        for (int i = 0; i < in_; ++i) ui += v[i] * Wl[tid * stride + i];
    }
    red[tid] = (tid < on) ? ui * ui : 0.f;
    __syncthreads();
    for (int st = 128; st > 0; st >>= 1) {
        if (tid < st) red[tid] += red[tid + st];
        __syncthreads();
    }
    if (tid == 0) {
        float nsq = red[0];
        float sv = nsq / fmaxf(sqrtf(nsq), 1e-12f);
        s_inv = 1.0f / sv;
    }
    __syncthreads();
    float inv = s_inv;
    for (int e = tid; e < n; e += 256) {
        int o = e >> shift, j = e & mask;
        dst[e] = f2b(Wl[o * stride + j] * inv);
    }
}

// ------- Kernel B: MFMA conv + 2x2 maxpool ----------------------------------
// grid: 16 b x 32 px-tiles (128 px = 2 image rows), 4 waves. Wn B-frags direct
// from global (24 KB, L1/L2-hot). LDS only xT (34.8 KB, reused as poolbuf)
// -> 4 blocks/CU.
__global__ __launch_bounds__(256) void convpool_mfma(
        const float* __restrict__ x, const unsigned short* __restrict__ wn,
        unsigned short* __restrict__ thetaT, unsigned short* __restrict__ phiT,
        unsigned short* __restrict__ gT) {
    __shared__ unsigned short smem[128 * 136];   // xT [px][c] s136; later poolbuf [80][132]
    int tid = threadIdx.x;
    int bb = blockIdx.x >> 5, tile = blockIdx.x & 31;
    int px0 = tile << 7;
    // stage xT: 4x4 register micro-transpose, 8B LDS writes
    const float4* x4 = (const float4*)x;
    {
        int p4 = tid & 31, cg = (tid >> 5) * 4;
        for (int k = 0; k < 4; ++k) {
            int cb = k * 32 + cg;
            float4 v0 = x4[(bb * 128 + cb + 0) * 1024 + tile * 32 + p4];
            float4 v1 = x4[(bb * 128 + cb + 1) * 1024 + tile * 32 + p4];
            float4 v2 = x4[(bb * 128 + cb + 2) * 1024 + tile * 32 + p4];
            float4 v3 = x4[(bb * 128 + cb + 3) * 1024 + tile * 32 + p4];
            float a0[4] = {v0.x, v0.y, v0.z, v0.w};
            float a1[4] = {v1.x, v1.y, v1.z, v1.w};
            float a2[4] = {v2.x, v2.y, v2.z, v2.w};
            float a3[4] = {v3.x, v3.y, v3.z, v3.w};
#pragma unroll
            for (int j = 0; j < 4; ++j) {
                s16x4 u; u[0] = (short)f2b(a0[j]); u[1] = (short)f2b(a1[j]);
                u[2] = (short)f2b(a2[j]); u[3] = (short)f2b(a3[j]);
                *(s16x4*)&smem[(p4 * 4 + j) * 136 + cb] = u;
            }
        }
    }
    __syncthreads();
    int lane = tid & 63, wv = tid >> 6;
    int q = lane >> 4, l = lane & 15;
    int pxw = wv * 32;
    f32x4 acc[2][6];
    const f32x4 z4 = {0.f, 0.f, 0.f, 0.f};
#pragma unroll
    for (int mt = 0; mt < 2; ++mt)
#pragma unroll
        for (int nt = 0; nt < 6; ++nt) acc[mt][nt] = z4;
#pragma unroll
    for (int kk = 0; kk < 4; ++kk) {
        bf16x8 a0 = *(const bf16x8*)&smem[(pxw + l) * 136 + kk * 32 + q * 8];
        bf16x8 a1 = *(const bf16x8*)&smem[(pxw + 16 + l) * 136 + kk * 32 + q * 8];
#pragma unroll
        for (int nt = 0; nt < 6; ++nt) {
            bf16x8 bw = *(const bf16x8*)&wn[(nt * 16 + l) * 128 + kk * 32 + q * 8];
            acc[0][nt] = __builtin_amdgcn_mfma_f32_16x16x32_bf16(a0, bw, acc[0][nt], 0, 0, 0);
            acc[1][nt] = __builtin_amdgcn_mfma_f32_16x16x32_bf16(a1, bw, acc[1][nt], 0, 0, 0);
        }
    }
    // theta (nt=0): write thetaT[s][c], c=l
#pragma unroll
    for (int mt = 0; mt < 2; ++mt)
#pragma unroll
        for (int r = 0; r < 4; ++r) {
            int s = px0 + pxw + mt * 16 + q * 4 + r;
            thetaT[(bb * 4096 + s) * 16 + l] = f2b(acc[mt][0][r]);
        }
    __syncthreads();   // all waves done reading xT region
    unsigned short* poolbuf = smem;   // [80 ch][px] stride 132
#pragma unroll
    for (int mt = 0; mt < 2; ++mt)
#pragma unroll
        for (int nt = 1; nt < 6; ++nt) {
            int ch = nt * 16 + l - 16;
#pragma unroll
            for (int r = 0; r < 4; ++r) {
                poolbuf[ch * 132 + pxw + mt * 16 + q * 4 + r] = f2b(acc[mt][nt][r]);
            }
        }
    __syncthreads();
    // 2x2 maxpool: image rows 2*tile, 2*tile+1 -> pooled row = tile
    for (int i = tid; i < 2560; i += 256) {
        int tcol = i & 31, ch = i >> 5;
        int base = ch * 132 + tcol * 2;
        float m0 = fmaxf(b2f(poolbuf[base]), b2f(poolbuf[base + 1]));
        float m1 = fmaxf(b2f(poolbuf[base + 64]), b2f(poolbuf[base + 65]));
        float m = fmaxf(m0, m1);
        int t = tile * 32 + tcol;
        if (ch < 16) phiT[(bb * 1024 + t) * 16 + ch] = f2b(m);
        else         gT[(bb * 64 + ch - 16) * 1024 + t] = f2b(m);
    }
}

// ------- Kernel C: MFMA fused attention, barrier-free -----------------------
// grid: 16 b x 32 s-tiles (128 s), 4 waves x 32 s. 32x32x16 mfma (exact K=16
// for S). phi/g fragments direct from global (L2-hot). Only wave-private psT
// in LDS -> ZERO __syncthreads.
// A layout 32x32x16: m=lane&31, k=(lane>>5)*8+j. B: n=lane&31, k=(lane>>5)*8+j.
// D: col=lane&31, row=(reg&3)+8*(reg>>2)+4*(lane>>5).
__global__ __launch_bounds__(256) void attn_mfma(
        const unsigned short* __restrict__ thetaT,
        const unsigned short* __restrict__ phiT,
        const unsigned short* __restrict__ gT,
        unsigned short* __restrict__ oT) {
    __shared__ unsigned short psT[128 * 72];    // [s][t] bf16, wave-private rows
    int tid = threadIdx.x;
    int bb = blockIdx.x >> 5, st = blockIdx.x & 31;
    int s0 = st << 7;
    int lane = tid & 63, wv = tid >> 6;
    int m = lane & 31, h = lane >> 5;           // mfma row lane, k-half
    int wsb = wv * 32;
    int sW = s0 + wsb;
    const f32x16 z16 = {0.f,0.f,0.f,0.f,0.f,0.f,0.f,0.f,0.f,0.f,0.f,0.f,0.f,0.f,0.f,0.f};

    // theta A-frag: A[m=s][k=c], 16 c exactly
    bf16x8 a_th = *(const bf16x8*)&thetaT[(bb * 4096 + sW + m) * 16 + h * 8];

    f32x16 acc[2];                               // O^T: 32 s x 64 c (2 c-tiles)
    acc[0] = z16; acc[1] = z16;
    float lp[16];
#pragma unroll
    for (int r = 0; r < 16; ++r) lp[r] = 0.f;

    const unsigned short* phB = &phiT[bb * 16384];
    const unsigned short* gB  = &gT[bb * 65536];

    for (int tc = 0; tc < 16; ++tc) {
        int t0 = tc << 6;
        // S = theta^T phi : 2 mfma cover 32 s x 64 t
        f32x16 sacc[2];
#pragma unroll
        for (int tg = 0; tg < 2; ++tg) {
            bf16x8 bp = *(const bf16x8*)&phB[(t0 + tg * 32 + m) * 16 + h * 8];
            sacc[tg] = __builtin_amdgcn_mfma_f32_32x32x16_bf16(a_th, bp, z16, 0, 0, 0);
        }
        // P = exp(S) -> psT rows (wave-private, no barrier)
#pragma unroll
        for (int tg = 0; tg < 2; ++tg)
#pragma unroll
            for (int r = 0; r < 16; ++r) {
                int row = (r & 3) + 8 * (r >> 2) + 4 * h;
                float e = __expf(sacc[tg][r]);
                lp[r] += e;
                psT[(wsb + row) * 72 + tg * 32 + m] = f2b_trunc(e);
            }
        // PV: O^T[s][c] += P[s][t] g^T[t][c], 4 K-steps of 16 t
#pragma unroll
        for (int kt = 0; kt < 4; ++kt) {
            bf16x8 ap = *(const bf16x8*)&psT[(wsb + m) * 72 + kt * 16 + h * 8];
#pragma unroll
            for (int cg = 0; cg < 2; ++cg) {
                bf16x8 bg = *(const bf16x8*)&gB[(cg * 32 + m) * 1024 + t0 + kt * 16 + h * 8];
                acc[cg] = __builtin_amdgcn_mfma_f32_32x32x16_bf16(ap, bg, acc[cg], 0, 0, 0);
            }
        }
    }
    // row sums: butterfly over the 32-lane half; every lane gets its 16 rows
    float inv[16];
#pragma unroll
    for (int r = 0; r < 16; ++r) {
        float v = lp[r];
        v += __shfl_xor(v, 1);
        v += __shfl_xor(v, 2);
        v += __shfl_xor(v, 4);
        v += __shfl_xor(v, 8);
        v += __shfl_xor(v, 16);
        inv[r] = 1.0f / v;
    }
    // write oT[s][c]: per (cg,r) a 64B-contiguous line across lanes
#pragma unroll
    for (int cg = 0; cg < 2; ++cg)
#pragma unroll
        for (int r = 0; r < 16; ++r) {
            int row = (r & 3) + 8 * (r >> 2) + 4 * h;
            oT[(bb * 4096 + sW + row) * 64 + cg * 32 + m] = f2b(acc[cg][r] * inv[r]);
        }
}

// ------- Kernel D: out = gamma * (Wo @ o) + x  (MFMA, no LDS, no barriers) --
// grid: 16 b x 64 px-tiles (64 px) = 1024 blocks (4/CU), 4 waves x 16 px.
__global__ __launch_bounds__(256) void outconv_mfma(
        const unsigned short* __restrict__ oT, const unsigned short* __restrict__ wo,
        const float* __restrict__ x, const float* __restrict__ gam,
        float* __restrict__ out) {
    int tid = threadIdx.x;
    int bb = blockIdx.x >> 6, tile = blockIdx.x & 63;
    int lane = tid & 63, wv = tid >> 6;
    int q = lane >> 4, l = lane & 15;
    int pxw = tile * 64 + wv * 16;
    // A-frags: 16 px x 64 c
    bf16x8 af[2];
#pragma unroll
    for (int kk = 0; kk < 2; ++kk)
        af[kk] = *(const bf16x8*)&oT[(bb * 4096 + pxw + l) * 64 + kk * 32 + q * 8];
    f32x4 acc[8];
    const f32x4 z4 = {0.f, 0.f, 0.f, 0.f};
#pragma unroll
    for (int nt = 0; nt < 8; ++nt) acc[nt] = z4;
#pragma unroll
    for (int kk = 0; kk < 2; ++kk)
#pragma unroll
        for (int nt = 0; nt < 8; ++nt) {
            bf16x8 bw = *(const bf16x8*)&wo[(nt * 16 + l) * 64 + kk * 32 + q * 8];
            acc[nt] = __builtin_amdgcn_mfma_f32_16x16x32_bf16(af[kk], bw, acc[nt], 0, 0, 0);
        }
    float gm = gam[0];
    const float4* x4 = (const float4*)x;
    float4* out4 = (float4*)out;
#pragma unroll
    for (int nt = 0; nt < 8; ++nt) {
        int oc = nt * 16 + l;
        int gi = (bb * 128 + oc) * 1024 + (pxw >> 2) + q;
        float4 xv = x4[gi];
        float4 r;
        r.x = gm * acc[nt][0] + xv.x;
        r.y = gm * acc[nt][1] + xv.y;
        r.z = gm * acc[nt][2] + xv.z;
        r.w = gm * acc[nt][3] + xv.w;
        out4[gi] = r;
    }
}

extern "C" void kernel_launch(void* const* d_in, const int* in_sizes, int n_in,
                              void* d_out, int out_size, void* d_ws, size_t ws_size,
                              hipStream_t stream) {
    const float* x  = (const float*)d_in[0];
    const float* wt = (const float*)d_in[1];
    const float* wp = (const float*)d_in[2];
    const float* wg = (const float*)d_in[3];
    const float* wo = (const float*)d_in[4];
    const float* ut = (const float*)d_in[5];
    const float* up = (const float*)d_in[6];
    const float* ug = (const float*)d_in[7];
    const float* uo = (const float*)d_in[8];
    const float* gm = (const float*)d_in[9];
    unsigned short* wsu = (unsigned short*)d_ws;
    float* out = (float*)d_out;

    sn4<<<4, 256, 0, stream>>>(wt, wp, wg, wo, ut, up, ug, uo, wsu);
    convpool_mfma<<<512, 256, 0, stream>>>(x, wsu + U_WN,
                                           wsu + U_TH, wsu + U_PHI, wsu + U_G);
    attn_mfma<<<512, 256, 0, stream>>>(wsu + U_TH, wsu + U_PHI, wsu + U_G, wsu + U_OT);
    outconv_mfma<<<1024, 256, 0, stream>>>(wsu + U_OT, wsu + U_WO, x, gm, out);
}